// Round 1
// baseline (88.237 us; speedup 1.0000x reference)
//
#include <hip/hip_runtime.h>
#include <stdint.h>

#define AS1 __attribute__((address_space(1)))
#define AS3 __attribute__((address_space(3)))

typedef __attribute__((ext_vector_type(4))) float f32x4;
typedef __attribute__((ext_vector_type(8))) short bf16x8;

static constexpr int N_ = 4, C_ = 256, HW_ = 4096;
static constexpr int CO_ = 256, KTAP = 9, KK = 2304;   // KK = C_*KTAP
static constexpr int NSTEP = KK / 32;                   // 72

static constexpr size_t NHWC_BYTES = (size_t)N_ * HW_ * C_ * 2;  // 8 MB
static constexpr size_t ABF_OFF    = NHWC_BYTES;
static constexpr size_t ABF_BYTES  = (size_t)CO_ * KK * 2;       // 1.18 MB

__device__ inline unsigned f2bf(float f) {
  unsigned u = __builtin_bit_cast(unsigned, f);
  unsigned r = u + 0x7FFFu + ((u >> 16) & 1u);
  return r >> 16;
}
__device__ inline float asf(unsigned u) { return __builtin_bit_cast(float, u); }

// ---------------- NCHW f32 -> NHWC bf16 ----------------
__global__ __launch_bounds__(256) void k_nchw_to_nhwc(const float* __restrict__ in,
                                                      unsigned short* __restrict__ nhwc) {
  __shared__ float tile[64][65];
  int b = blockIdx.x;
  int n = b >> 8, cg = (b >> 6) & 3, hwg = b & 63;
  int c0 = cg * 64, hw0 = hwg * 64;
  int t = threadIdx.x;
  int col = t & 63, r0 = t >> 6;
  const float* src = in + (size_t)(n * C_ + c0) * HW_ + hw0;
#pragma unroll
  for (int i = 0; i < 16; ++i) {
    int row = r0 + i * 4;
    tile[row][col] = src[(size_t)row * HW_ + col];
  }
  __syncthreads();
  int pr = t >> 2, cc0 = (t & 3) * 16;
  unsigned us[8];
#pragma unroll
  for (int i = 0; i < 8; ++i) {
    unsigned lo = f2bf(tile[cc0 + 2 * i][pr]);
    unsigned hi = f2bf(tile[cc0 + 2 * i + 1][pr]);
    us[i] = lo | (hi << 16);
  }
  unsigned* dst = (unsigned*)(nhwc + (size_t)(n * HW_ + hw0 + pr) * C_ + c0 + cc0);
  ((uint4*)dst)[0] = make_uint4(us[0], us[1], us[2], us[3]);
  ((uint4*)dst)[1] = make_uint4(us[4], us[5], us[6], us[7]);
}

// ---------------- filter f32 [O][C][3][3] -> bf16 [O][k*256+c] ----------------
__global__ __launch_bounds__(256) void k_prep_filter(const float* __restrict__ filt,
                                                     unsigned short* __restrict__ abf) {
  int gid = blockIdx.x * 256 + threadIdx.x;
  int o = gid >> 8, c = gid & 255;
  const float* f = filt + (size_t)(o * C_ + c) * KTAP;
#pragma unroll
  for (int k = 0; k < KTAP; ++k)
    abf[(size_t)o * KK + k * C_ + c] = (unsigned short)f2bf(f[k]);
}

// ---------------- fused sample + GEMM ----------------
// grid 256 blocks (one per output row), 512 threads (8 waves)
// out tile: 256 (Cout) x 64 (px). K-dim = tap*256 + c, BK=32 (one tap / step).
__global__ __launch_bounds__(512) void k_dcn_gemm(const unsigned short* __restrict__ nhwc,
                                                  const unsigned short* __restrict__ abf,
                                                  const float* __restrict__ offs,
                                                  const float* __restrict__ msk,
                                                  float* __restrict__ out) {
  __shared__ unsigned short Al[256 * 32];  // [o][k], 64B rows, XOR-swizzled 16B chunks
  __shared__ unsigned short Bl[64 * 32];   // [px][k], same swizzle
  __shared__ float recW[KTAP * 64 * 4];
  __shared__ unsigned recA[KTAP * 64 * 4];

  int b = blockIdx.x;
  int n = b >> 6;
  int ho = b & 63;
  int hw0 = ho << 6;
  int t = threadIdx.x;

  // --- per (pixel, tap) sampling records ---
  for (int r = t; r < 576; r += 512) {
    int pl = r / 9;
    int tap = r - pl * 9;
    int hw = hw0 + pl;
    float dy = offs[(size_t)(n * 18 + 2 * tap) * HW_ + hw];
    float dx = offs[(size_t)(n * 18 + 2 * tap + 1) * HW_ + hw];
    float mk = msk[(size_t)(n * 9 + tap) * HW_ + hw];
    float y = (float)(ho - 1 + tap / 3) + dy;
    float x = (float)(pl - 1 + tap % 3) + dx;
    float fy = floorf(y), fx = floorf(x);
    float ly = y - fy, lx = x - fx;
    int y0 = (int)fy, x0 = (int)fx;
    int y1 = y0 + 1, x1 = x0 + 1;
    float vy0 = (y0 >= 0 && y0 < 64) ? 1.f : 0.f;
    float vy1 = (y1 >= 0 && y1 < 64) ? 1.f : 0.f;
    float vx0 = (x0 >= 0 && x0 < 64) ? 1.f : 0.f;
    float vx1 = (x1 >= 0 && x1 < 64) ? 1.f : 0.f;
    int y0c = min(max(y0, 0), 63), y1c = min(max(y1, 0), 63);
    int x0c = min(max(x0, 0), 63), x1c = min(max(x1, 0), 63);
    int base = (tap * 64 + pl) * 4;
    recW[base + 0] = (1.f - ly) * (1.f - lx) * mk * vy0 * vx0;
    recW[base + 1] = (1.f - ly) * lx * mk * vy0 * vx1;
    recW[base + 2] = ly * (1.f - lx) * mk * vy1 * vx0;
    recW[base + 3] = ly * lx * mk * vy1 * vx1;
    recA[base + 0] = (unsigned)((y0c * 64 + x0c) * 512);  // byte offset of channel row
    recA[base + 1] = (unsigned)((y0c * 64 + x1c) * 512);
    recA[base + 2] = (unsigned)((y1c * 64 + x0c) * 512);
    recA[base + 3] = (unsigned)((y1c * 64 + x1c) * 512);
  }
  __syncthreads();

  int lane = t & 63, wv = t >> 6;
  int wm0 = (wv >> 1) * 64, wn0 = (wv & 1) * 32;
  int p_b = t >> 3, cg = t & 7;  // B-build role: pixel p_b, channels cg*4..+4

  f32x4 acc[4][2];
#pragma unroll
  for (int mi = 0; mi < 4; ++mi)
#pragma unroll
    for (int ni = 0; ni < 2; ++ni) acc[mi][ni] = (f32x4){0.f, 0.f, 0.f, 0.f};

  const char* nbase = (const char*)nhwc + (size_t)n * HW_ * C_ * 2;

  for (int s = 0; s < NSTEP; ++s) {
    int tap = s >> 3;
    int c0 = (s & 7) << 5;

    // --- stage A tile (256x32 bf16) via global_load_lds, pre-swizzled source ---
#pragma unroll
    for (int j = 0; j < 2; ++j) {
      int L = (t + j * 512) * 16;  // linear byte offset in Al
      int row = L >> 6;
      int q = ((L >> 4) & 3) ^ ((row >> 1) & 3);
      const unsigned short* src = abf + (size_t)row * KK + tap * C_ + c0 + q * 8;
      __builtin_amdgcn_global_load_lds((const AS1 void*)src, (AS3 void*)((char*)Al + L), 16, 0, 0);
    }

    // --- build B tile: bilinear sample 4 channels for (p_b, tap) ---
    {
      int rbase = (tap * 64 + p_b) * 4;
      f32x4 w = *(const f32x4*)&recW[rbase];
      uint4 a = *(const uint4*)&recA[rbase];
      const char* cb = nbase + (size_t)(c0 + cg * 4) * 2;
      uint2 q00 = *(const uint2*)(cb + a.x);
      uint2 q01 = *(const uint2*)(cb + a.y);
      uint2 q10 = *(const uint2*)(cb + a.z);
      uint2 q11 = *(const uint2*)(cb + a.w);
      float r0 = w.x * asf(q00.x << 16) + w.y * asf(q01.x << 16) +
                 w.z * asf(q10.x << 16) + w.w * asf(q11.x << 16);
      float r1 = w.x * asf(q00.x & 0xffff0000u) + w.y * asf(q01.x & 0xffff0000u) +
                 w.z * asf(q10.x & 0xffff0000u) + w.w * asf(q11.x & 0xffff0000u);
      float r2 = w.x * asf(q00.y << 16) + w.y * asf(q01.y << 16) +
                 w.z * asf(q10.y << 16) + w.w * asf(q11.y << 16);
      float r3 = w.x * asf(q00.y & 0xffff0000u) + w.y * asf(q01.y & 0xffff0000u) +
                 w.z * asf(q10.y & 0xffff0000u) + w.w * asf(q11.y & 0xffff0000u);
      unsigned u0 = f2bf(r0) | (f2bf(r1) << 16);
      unsigned u1 = f2bf(r2) | (f2bf(r3) << 16);
      int qb = (cg >> 1) ^ ((p_b >> 1) & 3);
      *(uint2*)((char*)Bl + p_b * 64 + qb * 16 + (cg & 1) * 8) = make_uint2(u0, u1);
    }
    __syncthreads();  // drains global_load_lds (vmcnt) + ds_writes

    // --- MFMA phase ---
    bf16x8 af[4], bfr[2];
#pragma unroll
    for (int mi = 0; mi < 4; ++mi) {
      int row = wm0 + mi * 16 + (lane & 15);
      int q = (lane >> 4) ^ ((row >> 1) & 3);
      af[mi] = *(const bf16x8*)((const char*)Al + row * 64 + q * 16);
    }
#pragma unroll
    for (int ni = 0; ni < 2; ++ni) {
      int row = wn0 + ni * 16 + (lane & 15);
      int q = (lane >> 4) ^ ((row >> 1) & 3);
      bfr[ni] = *(const bf16x8*)((const char*)Bl + row * 64 + q * 16);
    }
#pragma unroll
    for (int mi = 0; mi < 4; ++mi)
#pragma unroll
      for (int ni = 0; ni < 2; ++ni)
        acc[mi][ni] = __builtin_amdgcn_mfma_f32_16x16x32_bf16(af[mi], bfr[ni], acc[mi][ni], 0, 0, 0);
    __syncthreads();
  }

  // --- epilogue: D col=lane&15 (px), row=(lane>>4)*4+j (o) ---
  float* ob = out + (size_t)n * CO_ * HW_;
#pragma unroll
  for (int mi = 0; mi < 4; ++mi)
#pragma unroll
    for (int ni = 0; ni < 2; ++ni)
#pragma unroll
      for (int j = 0; j < 4; ++j) {
        int o = wm0 + mi * 16 + (lane >> 4) * 4 + j;
        int hw = hw0 + wn0 + ni * 16 + (lane & 15);
        ob[(size_t)o * HW_ + hw] = acc[mi][ni][j];
      }
}

extern "C" void kernel_launch(void* const* d_in, const int* in_sizes, int n_in,
                              void* d_out, int out_size, void* d_ws, size_t ws_size,
                              hipStream_t stream) {
  const float* inp  = (const float*)d_in[0];
  const float* filt = (const float*)d_in[1];
  const float* offs = (const float*)d_in[2];
  const float* msk  = (const float*)d_in[3];
  float* out = (float*)d_out;
  if (ws_size < ABF_OFF + ABF_BYTES) return;  // need ~9.6 MB scratch
  unsigned short* nhwc = (unsigned short*)d_ws;
  unsigned short* abf  = (unsigned short*)((char*)d_ws + ABF_OFF);

  k_nchw_to_nhwc<<<1024, 256, 0, stream>>>(inp, nhwc);
  k_prep_filter<<<256, 256, 0, stream>>>(filt, abf);
  k_dcn_gemm<<<256, 512, 0, stream>>>(nhwc, abf, offs, msk, out);
}

// Round 2
// 56.349 us; speedup vs baseline: 1.5659x; 1.5659x over previous
//
#include <hip/hip_runtime.h>
#include <stdint.h>

typedef __attribute__((ext_vector_type(4))) float f32x4;
typedef __attribute__((ext_vector_type(8))) short bf16x8;

static constexpr int N_ = 4, C_ = 256, HW_ = 4096;
static constexpr int CO_ = 256, KTAP = 9, KK = 2304;  // KK = C_*KTAP
static constexpr int NSTEP = 72;                      // KK / 32
static constexpr int A_STEP_BYTES = 16 * 64 * 16;     // one K-step plane of A: 16KB

static constexpr size_t NHWC_BYTES = (size_t)N_ * HW_ * C_ * 2;  // 8 MB
static constexpr size_t ABF_OFF    = NHWC_BYTES;
static constexpr size_t ABF_BYTES  = (size_t)NSTEP * A_STEP_BYTES;  // 1.18 MB

__device__ inline unsigned f2bf(float f) {
  unsigned u = __builtin_bit_cast(unsigned, f);
  unsigned r = u + 0x7FFFu + ((u >> 16) & 1u);
  return r >> 16;
}
__device__ inline float asf(unsigned u) { return __builtin_bit_cast(float, u); }

// ---------------- NCHW f32 -> NHWC bf16 ----------------
__global__ __launch_bounds__(256) void k_nchw_to_nhwc(const float* __restrict__ in,
                                                      unsigned short* __restrict__ nhwc) {
  __shared__ float tile[64][65];
  int b = blockIdx.x;
  int n = b >> 8, cg = (b >> 6) & 3, hwg = b & 63;
  int c0 = cg * 64, hw0 = hwg * 64;
  int t = threadIdx.x;
  int col = t & 63, r0 = t >> 6;
  const float* src = in + (size_t)(n * C_ + c0) * HW_ + hw0;
#pragma unroll
  for (int i = 0; i < 16; ++i) {
    int row = r0 + i * 4;
    tile[row][col] = src[(size_t)row * HW_ + col];
  }
  __syncthreads();
  int pr = t >> 2, cc0 = (t & 3) * 16;
  unsigned us[8];
#pragma unroll
  for (int i = 0; i < 8; ++i) {
    unsigned lo = f2bf(tile[cc0 + 2 * i][pr]);
    unsigned hi = f2bf(tile[cc0 + 2 * i + 1][pr]);
    us[i] = lo | (hi << 16);
  }
  unsigned* dst = (unsigned*)(nhwc + (size_t)(n * HW_ + hw0 + pr) * C_ + c0 + cc0);
  ((uint4*)dst)[0] = make_uint4(us[0], us[1], us[2], us[3]);
  ((uint4*)dst)[1] = make_uint4(us[4], us[5], us[6], us[7]);
}

// ---------------- filter f32 [O][C][3][3] -> bf16 fragment-major ----------------
// abf2[((s*16 + rb)*64 + lane)*8 + j]  where s = tap*8 + (c>>5), rb = o>>4,
// lane = ((c>>3)&3)*16 + (o&15), j = c&7.  Reader: wave loads 16B/lane per frag.
__global__ __launch_bounds__(256) void k_prep_filter(const float* __restrict__ filt,
                                                     unsigned short* __restrict__ abf2) {
  int gid = blockIdx.x * 256 + threadIdx.x;
  int o = gid >> 8, c = gid & 255;
  const float* f = filt + (size_t)(o * C_ + c) * KTAP;
  int rb = o >> 4;
  int lane = ((c >> 3) & 3) * 16 + (o & 15);
  int j = c & 7;
#pragma unroll
  for (int tap = 0; tap < KTAP; ++tap) {
    int s = tap * 8 + (c >> 5);
    abf2[((size_t)(s * 16 + rb) * 64 + lane) * 8 + j] = (unsigned short)f2bf(f[tap]);
  }
}

// bilinear combine of 4 channels from 4 corners -> 4 bf16 (8B)
__device__ __forceinline__ void buildB(const uint2* g, f32x4 w, unsigned short* dst) {
  float r0 = w.x * asf(g[0].x << 16) + w.y * asf(g[1].x << 16) +
             w.z * asf(g[2].x << 16) + w.w * asf(g[3].x << 16);
  float r1 = w.x * asf(g[0].x & 0xffff0000u) + w.y * asf(g[1].x & 0xffff0000u) +
             w.z * asf(g[2].x & 0xffff0000u) + w.w * asf(g[3].x & 0xffff0000u);
  float r2 = w.x * asf(g[0].y << 16) + w.y * asf(g[1].y << 16) +
             w.z * asf(g[2].y << 16) + w.w * asf(g[3].y << 16);
  float r3 = w.x * asf(g[0].y & 0xffff0000u) + w.y * asf(g[1].y & 0xffff0000u) +
             w.z * asf(g[2].y & 0xffff0000u) + w.w * asf(g[3].y & 0xffff0000u);
  *(uint2*)dst = make_uint2(f2bf(r0) | (f2bf(r1) << 16), f2bf(r2) | (f2bf(r3) << 16));
}

#define MFMA_BF16 __builtin_amdgcn_mfma_f32_16x16x32_bf16

// One pipelined K-step. GCON/WCON: gather bank+weights consumed (build B(S+1)).
// GISS/WISS: bank filled with g(S+2). AC*: A frags for step S. AN*: loads A(S+1).
// RDP/WRP: literal LDS buffer parities (read B(S), write B(S+1)).
#define PIPE_STEP(S, GCON, WCON, GISS, WISS, AC0, AC1, AN0, AN1, RDP, WRP)            \
  do {                                                                                \
    int s1_ = (S) + 1; if (s1_ >= NSTEP) s1_ = NSTEP - 1;                             \
    int s2_ = (S) + 2; if (s2_ >= NSTEP) s2_ = NSTEP - 1;                             \
    AN0 = *(const bf16x8*)(aoff0 + (size_t)s1_ * A_STEP_BYTES);                       \
    AN1 = *(const bf16x8*)(aoff1 + (size_t)s1_ * A_STEP_BYTES);                       \
    if ((s2_ & 7) == 0) {                                                             \
      int tp_ = s2_ >> 3;                                                             \
      raS = *(const uint4*)&recA[(tp_ * 64 + p_b) * 4];                               \
      wS  = *(const f32x4*)&recW[(tp_ * 64 + p_b) * 4];                               \
    }                                                                                 \
    {                                                                                 \
      unsigned sc_ = (unsigned)((s2_ & 7) * 64);                                      \
      GISS[0] = *(const uint2*)(nb_t + raS.x + sc_);                                  \
      GISS[1] = *(const uint2*)(nb_t + raS.y + sc_);                                  \
      GISS[2] = *(const uint2*)(nb_t + raS.z + sc_);                                  \
      GISS[3] = *(const uint2*)(nb_t + raS.w + sc_);                                  \
    }                                                                                 \
    WISS = wS;                                                                        \
    __builtin_amdgcn_sched_barrier(0);                                                \
    {                                                                                 \
      const char* bb_ = (const char*)&Bl[RDP][0] + boff;                              \
      bf16x8 b0_ = *(const bf16x8*)(bb_);                                             \
      bf16x8 b1_ = *(const bf16x8*)(bb_ + 1280);                                      \
      bf16x8 b2_ = *(const bf16x8*)(bb_ + 2560);                                      \
      bf16x8 b3_ = *(const bf16x8*)(bb_ + 3840);                                      \
      __builtin_amdgcn_s_setprio(1);                                                  \
      acc[0][0] = MFMA_BF16(AC0, b0_, acc[0][0], 0, 0, 0);                            \
      acc[1][0] = MFMA_BF16(AC1, b0_, acc[1][0], 0, 0, 0);                            \
      acc[0][1] = MFMA_BF16(AC0, b1_, acc[0][1], 0, 0, 0);                            \
      acc[1][1] = MFMA_BF16(AC1, b1_, acc[1][1], 0, 0, 0);                            \
      acc[0][2] = MFMA_BF16(AC0, b2_, acc[0][2], 0, 0, 0);                            \
      acc[1][2] = MFMA_BF16(AC1, b2_, acc[1][2], 0, 0, 0);                            \
      acc[0][3] = MFMA_BF16(AC0, b3_, acc[0][3], 0, 0, 0);                            \
      acc[1][3] = MFMA_BF16(AC1, b3_, acc[1][3], 0, 0, 0);                            \
      __builtin_amdgcn_s_setprio(0);                                                  \
    }                                                                                 \
    buildB(GCON, WCON, (WRP) ? bw1 : bw0);                                            \
    asm volatile("s_waitcnt lgkmcnt(0)" ::: "memory");                                \
    __builtin_amdgcn_s_barrier();                                                     \
    asm volatile("" ::: "memory");                                                    \
  } while (0)

// ---------------- fused sample + GEMM ----------------
// 256 blocks (one per output row) x 512 threads (8 waves, wave tile 32 Cout x 64 px)
__global__ __launch_bounds__(512, 2) void k_dcn_gemm(const unsigned short* __restrict__ nhwc,
                                                     const unsigned short* __restrict__ abf2,
                                                     const float* __restrict__ offs,
                                                     const float* __restrict__ msk,
                                                     float* __restrict__ out) {
  __shared__ __align__(16) unsigned short Bl[2][64 * 40];  // 80B rows (pad vs 64)
  __shared__ float recW[KTAP * 64 * 4];
  __shared__ unsigned recA[KTAP * 64 * 4];

  int bid = blockIdx.x;
  int b = ((bid & 7) << 5) | (bid >> 3);  // XCD-aware swizzle (bijective, 256%8==0)
  int n = b >> 6;
  int ho = b & 63;
  int hw0 = ho << 6;
  int t = threadIdx.x;

  // --- per (pixel, tap) sampling records ---
  for (int r = t; r < 576; r += 512) {
    int pl = r / 9;
    int tap = r - pl * 9;
    int hw = hw0 + pl;
    float dy = offs[(size_t)(n * 18 + 2 * tap) * HW_ + hw];
    float dx = offs[(size_t)(n * 18 + 2 * tap + 1) * HW_ + hw];
    float mk = msk[(size_t)(n * 9 + tap) * HW_ + hw];
    float y = (float)(ho - 1 + tap / 3) + dy;
    float x = (float)(pl - 1 + tap % 3) + dx;
    float fy = floorf(y), fx = floorf(x);
    float ly = y - fy, lx = x - fx;
    int y0 = (int)fy, x0 = (int)fx;
    int y1 = y0 + 1, x1 = x0 + 1;
    float vy0 = (y0 >= 0 && y0 < 64) ? 1.f : 0.f;
    float vy1 = (y1 >= 0 && y1 < 64) ? 1.f : 0.f;
    float vx0 = (x0 >= 0 && x0 < 64) ? 1.f : 0.f;
    float vx1 = (x1 >= 0 && x1 < 64) ? 1.f : 0.f;
    int y0c = min(max(y0, 0), 63), y1c = min(max(y1, 0), 63);
    int x0c = min(max(x0, 0), 63), x1c = min(max(x1, 0), 63);
    int base = (tap * 64 + pl) * 4;
    recW[base + 0] = (1.f - ly) * (1.f - lx) * mk * vy0 * vx0;
    recW[base + 1] = (1.f - ly) * lx * mk * vy0 * vx1;
    recW[base + 2] = ly * (1.f - lx) * mk * vy1 * vx0;
    recW[base + 3] = ly * lx * mk * vy1 * vx1;
    recA[base + 0] = (unsigned)((y0c * 64 + x0c) * 512);
    recA[base + 1] = (unsigned)((y0c * 64 + x1c) * 512);
    recA[base + 2] = (unsigned)((y1c * 64 + x0c) * 512);
    recA[base + 3] = (unsigned)((y1c * 64 + x1c) * 512);
  }
  __syncthreads();

  int lane = t & 63, wv = t >> 6;
  int p_b = t >> 3, cg = t & 7;

  const char* aoff0 = (const char*)abf2 + ((wv * 2 + 0) * 64 + lane) * 16;
  const char* aoff1 = (const char*)abf2 + ((wv * 2 + 1) * 64 + lane) * 16;
  const char* nb_t = (const char*)nhwc + (size_t)n * HW_ * C_ * 2 + cg * 8;
  unsigned short* bw0 = &Bl[0][p_b * 40 + cg * 4];
  unsigned short* bw1 = &Bl[1][p_b * 40 + cg * 4];
  const int boff = ((lane & 15) * 40 + (lane >> 4) * 8) * 2;

  f32x4 acc[2][4];
#pragma unroll
  for (int mi = 0; mi < 2; ++mi)
#pragma unroll
    for (int ni = 0; ni < 4; ++ni) acc[mi][ni] = (f32x4){0.f, 0.f, 0.f, 0.f};

  uint2 gA[4], gB[4];
  f32x4 wA, wB, wS;
  uint4 raS;

  // --- prologue: issue g(0), g(1), A(0); build B(0) ---
  raS = *(const uint4*)&recA[p_b * 4];  // tap 0
  wS  = *(const f32x4*)&recW[p_b * 4];
  gA[0] = *(const uint2*)(nb_t + raS.x);
  gA[1] = *(const uint2*)(nb_t + raS.y);
  gA[2] = *(const uint2*)(nb_t + raS.z);
  gA[3] = *(const uint2*)(nb_t + raS.w);
  wA = wS;
  gB[0] = *(const uint2*)(nb_t + raS.x + 64);  // step 1: channels 32..63
  gB[1] = *(const uint2*)(nb_t + raS.y + 64);
  gB[2] = *(const uint2*)(nb_t + raS.z + 64);
  gB[3] = *(const uint2*)(nb_t + raS.w + 64);
  wB = wS;
  bf16x8 afc0 = *(const bf16x8*)(aoff0);
  bf16x8 afc1 = *(const bf16x8*)(aoff1);
  bf16x8 afn0, afn1;

  buildB(gA, wA, bw0);
  asm volatile("s_waitcnt lgkmcnt(0)" ::: "memory");
  __builtin_amdgcn_s_barrier();
  asm volatile("" ::: "memory");

  // --- main loop: iter s consumes B(s), builds B(s+1), prefetches A(s+1), g(s+2) ---
  for (int s = 0; s < NSTEP; s += 2) {
    PIPE_STEP(s,     gB, wB, gA, wA, afc0, afc1, afn0, afn1, 0, 1);
    PIPE_STEP(s + 1, gA, wA, gB, wB, afn0, afn1, afc0, afc1, 1, 0);
  }

  // --- epilogue: D row = Cout, col = px ---
  float* ob = out + (size_t)n * CO_ * HW_ + hw0;
#pragma unroll
  for (int mi = 0; mi < 2; ++mi)
#pragma unroll
    for (int ni = 0; ni < 4; ++ni)
#pragma unroll
      for (int j = 0; j < 4; ++j) {
        int o = wv * 32 + mi * 16 + (lane >> 4) * 4 + j;
        int hw = ni * 16 + (lane & 15);
        ob[(size_t)o * HW_ + hw] = acc[mi][ni][j];
      }
}

extern "C" void kernel_launch(void* const* d_in, const int* in_sizes, int n_in,
                              void* d_out, int out_size, void* d_ws, size_t ws_size,
                              hipStream_t stream) {
  const float* inp  = (const float*)d_in[0];
  const float* filt = (const float*)d_in[1];
  const float* offs = (const float*)d_in[2];
  const float* msk  = (const float*)d_in[3];
  float* out = (float*)d_out;
  if (ws_size < ABF_OFF + ABF_BYTES) return;  // ~9.6 MB scratch
  unsigned short* nhwc = (unsigned short*)d_ws;
  unsigned short* abf2 = (unsigned short*)((char*)d_ws + ABF_OFF);

  k_nchw_to_nhwc<<<1024, 256, 0, stream>>>(inp, nhwc);
  k_prep_filter<<<256, 256, 0, stream>>>(filt, abf2);
  k_dcn_gemm<<<256, 512, 0, stream>>>(nhwc, abf2, offs, msk, out);
}